// Round 1
// baseline (184.246 us; speedup 1.0000x reference)
//
#include <hip/hip_runtime.h>
#include <hip/hip_bf16.h>

typedef __attribute__((ext_vector_type(8))) short short8;
typedef __attribute__((ext_vector_type(4))) float f32x4;

#define NT 65536
#define KC 256

__device__ __forceinline__ unsigned short f2bf(float f) {
    union { float f; unsigned int u; } v; v.f = f;
    unsigned int u = v.u;
    unsigned int r = (u + 0x7fffu + ((u >> 16) & 1u)) >> 16;  // RNE
    return (unsigned short)r;
}

// ---------------- prep: build bf16 B panel (w/beta interleaved in 64-groups) + per-k params ----------------
// Bc row n: gidx=n>>7, j=n&127; j<64 -> w[64*gidx+j], else beta[64*gidx+j-64]
// prm layout (per source, 5*KC floats): [0:256)=||w_k||^2, [256)=gam^2, [512)=eta^2, [768)=alpha, [1024)=sig^2
__global__ void prep_kernel(const float* __restrict__ w, const float* __restrict__ beta,
                            const float* __restrict__ alpha, const float* __restrict__ sig,
                            const float* __restrict__ eta, const float* __restrict__ gam,
                            unsigned short* __restrict__ bc, float* __restrict__ prm, int P) {
    __shared__ float red[2];
    const int n = blockIdx.x;          // 0..511
    const int tid = threadIdx.x;       // 128 threads
    const int gidx = n >> 7;
    const int j = n & 127;
    const int k = 64 * gidx + (j & 63);
    const bool isw = (j < 64);
    const float* src = (isw ? w : beta) + (size_t)k * P;
    unsigned short* dst = bc + (size_t)n * P;
    float ss = 0.f;
    for (int c = tid; c < P; c += 128) {
        float f = src[c];
        dst[c] = f2bf(f);
        if (isw) ss += f * f;
    }
#pragma unroll
    for (int m = 1; m < 64; m <<= 1) ss += __shfl_xor(ss, m);
    if ((tid & 63) == 0) red[tid >> 6] = ss;
    __syncthreads();
    if (isw && tid == 0) prm[k] = red[0] + red[1];
    if (n == 0) {
        for (int kk = tid; kk < KC; kk += 128) {
            float g = gam[kk], e = eta[kk];
            prm[KC + kk]     = g * g;
            prm[2 * KC + kk] = e * e;
            prm[3 * KC + kk] = alpha[kk];
            prm[4 * KC + kk] = sig[kk] * sig[kk];
        }
    }
}

// ---------------- fused: GEMM (x@w^T, x@beta^T) + RBF epilogue, per source ----------------
// grid: 1536 blocks (512 per source), 512 threads (8 waves: wr=wave>>1 in 0..3, wc=wave&1)
// block tile: 128 rows x 512 cols, K streamed in 32-steps, double-buffered LDS
__global__ __launch_bounds__(512, 2)
void fused_kernel(const float* __restrict__ x0, const float* __restrict__ x1, const float* __restrict__ x2,
                  const unsigned short* __restrict__ bcAll, const float* __restrict__ prmAll,
                  float* __restrict__ out) {
    __shared__ unsigned short As[2][128 * 32];
    __shared__ unsigned short Bs[2][512 * 32];
    __shared__ float xn2[128];
    __shared__ float prm[5 * KC];
    __shared__ float part[2][128][4];

    const int bx = blockIdx.x;
    const int s  = bx >> 9;
    const int mb = bx & 511;
    const int P  = (s == 0) ? 512 : ((s == 1) ? 256 : 128);
    const int NS = P >> 5;
    const float* x = (s == 0) ? x0 : ((s == 1) ? x1 : x2);
    const unsigned short* Bc = bcAll + ((s == 0) ? 0 : ((s == 1) ? (512 * 512) : (512 * 512 + 512 * 256)));
    const float* prms = prmAll + s * 5 * KC;
    const int row0 = mb * 128;

    const int tid  = threadIdx.x;
    const int lane = tid & 63;
    const int wave = tid >> 6;
    const int wr = wave >> 1;
    const int wc = wave & 1;
    const int l15 = lane & 15;
    const int l4  = lane >> 4;

    // params -> LDS
    for (int i = tid; i < 5 * KC; i += 512) prm[i] = prms[i];

    f32x4 acc0[16], acc1[16];
#pragma unroll
    for (int i = 0; i < 16; i++) { acc0[i] = (f32x4){0.f,0.f,0.f,0.f}; acc1[i] = (f32x4){0.f,0.f,0.f,0.f}; }

    // A staging assignment: thread -> (row = tid>>2, 8-float segment = tid&3)
    const int arow = tid >> 2;
    const int aseg = tid & 3;
    const float* xrow = x + (size_t)(row0 + arow) * P + aseg * 8;
    float ss = 0.f;

    // prologue: stage ks=0 into buf 0
    {
        float4 a0 = *(const float4*)(xrow);
        float4 a1 = *(const float4*)(xrow + 4);
        ss += a0.x*a0.x + a0.y*a0.y + a0.z*a0.z + a0.w*a0.w;
        ss += a1.x*a1.x + a1.y*a1.y + a1.z*a1.z + a1.w*a1.w;
        union { unsigned short u[8]; short8 v; } pk;
        pk.u[0]=f2bf(a0.x); pk.u[1]=f2bf(a0.y); pk.u[2]=f2bf(a0.z); pk.u[3]=f2bf(a0.w);
        pk.u[4]=f2bf(a1.x); pk.u[5]=f2bf(a1.y); pk.u[6]=f2bf(a1.z); pk.u[7]=f2bf(a1.w);
        *(short8*)(&As[0][arow * 32 + aseg * 8]) = pk.v;
#pragma unroll
        for (int i = 0; i < 4; i++) {
            int u = i * 512 + tid;
            int col = u >> 2, g = u & 3;
            uint4 bv = *(const uint4*)(Bc + (size_t)col * P + g * 8);
            *(uint4*)(&Bs[0][u * 8]) = bv;
        }
    }
    __syncthreads();

    int buf = 0;
    for (int ks = 0; ks < NS; ks++) {
        const bool more = (ks + 1 < NS);
        float4 a0, a1; uint4 bv[4];
        if (more) {
            a0 = *(const float4*)(xrow + (ks + 1) * 32);
            a1 = *(const float4*)(xrow + (ks + 1) * 32 + 4);
#pragma unroll
            for (int i = 0; i < 4; i++) {
                int u = i * 512 + tid;
                int col = u >> 2, g = u & 3;
                bv[i] = *(const uint4*)(Bc + (size_t)col * P + (ks + 1) * 32 + g * 8);
            }
        }
        // compute on buf
        const int rA = (32 * wr + l15) * 32 + l4 * 8;
        short8 af0 = *(const short8*)(&As[buf][rA]);
        short8 af1 = *(const short8*)(&As[buf][rA + 16 * 32]);
#pragma unroll
        for (int cf = 0; cf < 16; cf++) {
            const int cB = (wc * 256 + cf * 16 + l15) * 32 + l4 * 8;
            short8 bfv = *(const short8*)(&Bs[buf][cB]);
            acc0[cf] = __builtin_amdgcn_mfma_f32_16x16x32_bf16(af0, bfv, acc0[cf], 0, 0, 0);
            acc1[cf] = __builtin_amdgcn_mfma_f32_16x16x32_bf16(af1, bfv, acc1[cf], 0, 0, 0);
        }
        if (more) {
            ss += a0.x*a0.x + a0.y*a0.y + a0.z*a0.z + a0.w*a0.w;
            ss += a1.x*a1.x + a1.y*a1.y + a1.z*a1.z + a1.w*a1.w;
            union { unsigned short u[8]; short8 v; } pk;
            pk.u[0]=f2bf(a0.x); pk.u[1]=f2bf(a0.y); pk.u[2]=f2bf(a0.z); pk.u[3]=f2bf(a0.w);
            pk.u[4]=f2bf(a1.x); pk.u[5]=f2bf(a1.y); pk.u[6]=f2bf(a1.z); pk.u[7]=f2bf(a1.w);
            *(short8*)(&As[buf ^ 1][arow * 32 + aseg * 8]) = pk.v;
#pragma unroll
            for (int i = 0; i < 4; i++) *(uint4*)(&Bs[buf ^ 1][(i * 512 + tid) * 8]) = bv[i];
        }
        __syncthreads();
        buf ^= 1;
    }

    // ||x_row||^2 finalize
    float sred = ss;
    sred += __shfl_xor(sred, 1);
    sred += __shfl_xor(sred, 2);
    if (aseg == 0) xn2[arow] = sred;
    __syncthreads();

    // epilogue: per-lane holds rows {32wr+16rf+4*l4+r}, cols {wc*256+16cf+l15}
    float xr[2][4];
#pragma unroll
    for (int rf = 0; rf < 2; rf++)
#pragma unroll
        for (int r = 0; r < 4; r++)
            xr[rf][r] = xn2[32 * wr + 16 * rf + 4 * l4 + r];

    float hxa[2][4] = {{0}}, mua[2][4] = {{0}}, s2a[2][4] = {{0}};
#pragma unroll
    for (int gi = 0; gi < 2; gi++) {
#pragma unroll
        for (int q = 0; q < 4; q++) {
            const int k = 128 * wc + 64 * gi + 16 * q + l15;
            const float wn2v = prm[k];
            const float g2v  = prm[KC + k];
            const float hv   = prm[2 * KC + k];
            const float alv  = prm[3 * KC + k];
            const float s2v  = prm[4 * KC + k];
            const int cw = gi * 8 + q, cb = cw + 4;
#pragma unroll
            for (int rf = 0; rf < 2; rf++) {
                const f32x4 aw = rf ? acc1[cw] : acc0[cw];
                const f32x4 ab = rf ? acc1[cb] : acc0[cb];
#pragma unroll
                for (int r = 0; r < 4; r++) {
                    float d2 = xr[rf][r] - 2.f * aw[r] + wn2v;
                    float a  = __expf(-g2v * d2);
                    float ah = a * hv;
                    hxa[rf][r] += ah;
                    mua[rf][r] += (ab[r] + alv) * ah;
                    s2a[rf][r] += s2v * ah * ah;
                }
            }
        }
    }

    // reduce over the 16 lanes holding the same rows (different k), then stash per-wc partials
#pragma unroll
    for (int rf = 0; rf < 2; rf++) {
#pragma unroll
        for (int r = 0; r < 4; r++) {
            float h = hxa[rf][r], m = mua[rf][r], g = s2a[rf][r];
#pragma unroll
            for (int msk = 1; msk < 16; msk <<= 1) {
                h += __shfl_xor(h, msk);
                m += __shfl_xor(m, msk);
                g += __shfl_xor(g, msk);
            }
            if (l15 == 0) {
                int row = 32 * wr + 16 * rf + 4 * l4 + r;
                part[wc][row][0] = h;
                part[wc][row][1] = m;
                part[wc][row][2] = g;
            }
        }
    }
    __syncthreads();
    if (tid < 128) {
        float h = part[0][tid][0] + part[1][tid][0];
        float m = part[0][tid][1] + part[1][tid][1];
        float g = part[0][tid][2] + part[1][tid][2];
        const int R = row0 + tid;
        out[(size_t)s * NT + R]            = m / h;              // mux_s
        out[(size_t)(4 + s) * NT + R]      = g / (h * h);        // sig2x_s
        out[(size_t)(8 + s) * NT + R]      = h;                  // hx_s
    }
}

// ---------------- combine: rows 3 of each output ----------------
__global__ void combine_kernel(const float* __restrict__ d0, const float* __restrict__ d1,
                               const float* __restrict__ d2, float* out) {
    const int t = blockIdx.x * 256 + threadIdx.x;
    const float sd0 = 1.f / (1.f + __expf(-d0[0]));
    const float sd1 = 1.f / (1.f + __expf(-d1[0]));
    const float sd2 = 1.f / (1.f + __expf(-d2[0]));
    const float hx0 = out[(size_t)8 * NT + t];
    const float hx1 = out[(size_t)9 * NT + t];
    const float hx2 = out[(size_t)10 * NT + t];
    const float c0 = hx0 * sd0, c1 = hx1 * sd1, c2 = hx2 * sd2;
    const float den = c0 + c1 + c2;
    const float muc = out[(size_t)0 * NT + t] * c0 + out[(size_t)1 * NT + t] * c1 + out[(size_t)2 * NT + t] * c2;
    const float sgc = out[(size_t)4 * NT + t] * c0 * c0 + out[(size_t)5 * NT + t] * c1 * c1 + out[(size_t)6 * NT + t] * c2 * c2;
    out[(size_t)3 * NT + t]  = muc / den;
    out[(size_t)7 * NT + t]  = sgc / (den * den);
    out[(size_t)11 * NT + t] = den;
}

extern "C" void kernel_launch(void* const* d_in, const int* in_sizes, int n_in,
                              void* d_out, int out_size, void* d_ws, size_t ws_size,
                              hipStream_t stream) {
    // input order per source i: x=8i, alpha=8i+1, beta=8i+2, sig=8i+3, eta=8i+4, gam=8i+5, w=8i+6, disc=8i+7
    const float* x0 = (const float*)d_in[0];
    const float* x1 = (const float*)d_in[8];
    const float* x2 = (const float*)d_in[16];

    unsigned short* bc = (unsigned short*)d_ws;                 // 512*(512+256+128) ushorts = 917504 B
    float* prmAll = (float*)((char*)d_ws + 917504);             // 3*5*256 floats
    float* out = (float*)d_out;

    const int Ps[3] = {512, 256, 128};
    const size_t bcoff[3] = {0, 512 * 512, 512 * 512 + 512 * 256};
    for (int s = 0; s < 3; s++) {
        const float* alpha = (const float*)d_in[8 * s + 1];
        const float* beta  = (const float*)d_in[8 * s + 2];
        const float* sig   = (const float*)d_in[8 * s + 3];
        const float* eta   = (const float*)d_in[8 * s + 4];
        const float* gam   = (const float*)d_in[8 * s + 5];
        const float* w     = (const float*)d_in[8 * s + 6];
        prep_kernel<<<512, 128, 0, stream>>>(w, beta, alpha, sig, eta, gam,
                                             bc + bcoff[s], prmAll + s * 5 * KC, Ps[s]);
    }
    fused_kernel<<<1536, 512, 0, stream>>>(x0, x1, x2, bc, prmAll, out);
    combine_kernel<<<256, 256, 0, stream>>>((const float*)d_in[7], (const float*)d_in[15],
                                            (const float*)d_in[23], out);
}

// Round 2
// 158.173 us; speedup vs baseline: 1.1648x; 1.1648x over previous
//
#include <hip/hip_runtime.h>
#include <hip/hip_bf16.h>

typedef __attribute__((ext_vector_type(8))) short short8;
typedef __attribute__((ext_vector_type(4))) float f32x4;

#define NT 65536
#define KC 256

__device__ __forceinline__ unsigned short f2bf(float f) {
    union { float f; unsigned int u; } v; v.f = f;
    unsigned int u = v.u;
    unsigned int r = (u + 0x7fffu + ((u >> 16) & 1u)) >> 16;  // RNE
    return (unsigned short)r;
}

__device__ __forceinline__ unsigned int cvt_pk_bf16(float lo, float hi) {
    unsigned int r;
    asm("v_cvt_pk_bf16_f32 %0, %1, %2" : "=v"(r) : "v"(lo), "v"(hi));
    return r;
}

// ---------------- prep: build bf16 B panel (w/beta interleaved in 64-groups) + per-k params ----------------
// Bc row n: gidx=n>>7, j=n&127; j<64 -> w[64*gidx+j], else beta[64*gidx+j-64]
// prm layout (per source, 5*KC floats): [0:256)=||w_k||^2, [256)=gam^2, [512)=eta^2, [768)=alpha, [1024)=sig^2
__global__ void prep_kernel(const float* __restrict__ w, const float* __restrict__ beta,
                            const float* __restrict__ alpha, const float* __restrict__ sig,
                            const float* __restrict__ eta, const float* __restrict__ gam,
                            unsigned short* __restrict__ bc, float* __restrict__ prm, int P) {
    __shared__ float red[2];
    const int n = blockIdx.x;          // 0..511
    const int tid = threadIdx.x;       // 128 threads
    const int gidx = n >> 7;
    const int j = n & 127;
    const int k = 64 * gidx + (j & 63);
    const bool isw = (j < 64);
    const float* src = (isw ? w : beta) + (size_t)k * P;
    unsigned short* dst = bc + (size_t)n * P;
    float ss = 0.f;
    for (int c = tid; c < P; c += 128) {
        float f = src[c];
        dst[c] = f2bf(f);
        if (isw) ss += f * f;
    }
#pragma unroll
    for (int m = 1; m < 64; m <<= 1) ss += __shfl_xor(ss, m);
    if ((tid & 63) == 0) red[tid >> 6] = ss;
    __syncthreads();
    if (isw && tid == 0) prm[k] = red[0] + red[1];
    if (n == 0) {
        for (int kk = tid; kk < KC; kk += 128) {
            float g = gam[kk], e = eta[kk];
            prm[KC + kk]     = g * g;
            prm[2 * KC + kk] = e * e;
            prm[3 * KC + kk] = alpha[kk];
            prm[4 * KC + kk] = sig[kk] * sig[kk];
        }
    }
}

// ---------------- fused: GEMM (x@w^T, x@beta^T) + RBF epilogue, per source ----------------
// grid: 1536 blocks (bx%3 = source, bx/3 = row-block), 512 threads, 8 waves in 2(row)x4(col) grid
// block tile: 128 rows x 512 cols, K streamed in 32-steps, double-buffered LDS.
// LDS rows are 64B (32 ushorts); 16B slots XOR-swizzled: phys_slot = log_slot ^ ((row>>1)&3)
// -> fragment ds_read_b128 across 16 consecutive rows hits all 8 bank-quads (2-way = free).
// B staged via global_load_lds (linear LDS dest) with pre-swizzled GLOBAL source (rule 21).
__global__ __launch_bounds__(512, 2)
void fused_kernel(const float* __restrict__ x0, const float* __restrict__ x1, const float* __restrict__ x2,
                  const unsigned short* __restrict__ bcAll, const float* __restrict__ prmAll,
                  float* __restrict__ out) {
    __shared__ unsigned short As[2][128 * 32];
    __shared__ unsigned short Bs[2][512 * 32];

    const int bx = blockIdx.x;
    const int s  = bx % 3;
    const int mb = bx / 3;
    const int P  = (s == 0) ? 512 : ((s == 1) ? 256 : 128);
    const int NS = P >> 5;
    const float* x = (s == 0) ? x0 : ((s == 1) ? x1 : x2);
    const unsigned short* Bc = bcAll + ((s == 0) ? 0 : ((s == 1) ? (512 * 512) : (512 * 512 + 512 * 256)));
    const float* prms = prmAll + s * 5 * KC;
    const int row0 = mb * 128;

    const int tid  = threadIdx.x;
    const int lane = tid & 63;
    const int wave = tid >> 6;
    const int wr = wave >> 2;   // 0..1
    const int wc = wave & 3;    // 0..3
    const int l15 = lane & 15;
    const int l4  = lane >> 4;  // 0..3
    const int fslot = l4 ^ ((l15 >> 1) & 3);   // swizzled slot for fragment reads

    f32x4 acc[4][8];
#pragma unroll
    for (int rf = 0; rf < 4; rf++)
#pragma unroll
        for (int cf = 0; cf < 8; cf++) acc[rf][cf] = (f32x4){0.f, 0.f, 0.f, 0.f};

    // A staging: thread -> (row = tid>>2, 8-float seg = tid&3), swizzled slot on write
    const int arow = tid >> 2;
    const int aseg = tid & 3;
    const int aslot = aseg ^ ((arow >> 1) & 3);
    const float* xrow = x + (size_t)(row0 + arow) * P + aseg * 8;
    float ss = 0.f;

    // B staging via global_load_lds: physical u = i*512+tid, LDS byte = u*16 (linear).
    // logical slot at phys (r, sp) is sp^((r>>1)&3) -> read that 16B from global.
    auto stageB = [&](int nb, int ks) {
#pragma unroll
        for (int i = 0; i < 4; i++) {
            const int u = i * 512 + tid;
            const int r = u >> 2;
            const int sl = (u & 3) ^ ((r >> 1) & 3);
            const unsigned short* src = Bc + (size_t)r * P + ks * 32 + sl * 8;
            unsigned short* dstbase = &Bs[nb][(i * 4096) + (wave << 9)];  // ushort units: i*8KB + wave*1KB
            __builtin_amdgcn_global_load_lds((const __attribute__((address_space(1))) void*)src,
                                             (__attribute__((address_space(3))) void*)dstbase, 16, 0, 0);
        }
    };

    // prologue: stage ks=0 into buf 0
    stageB(0, 0);
    {
        float4 a0 = *(const float4*)(xrow);
        float4 a1 = *(const float4*)(xrow + 4);
        ss += a0.x*a0.x + a0.y*a0.y + a0.z*a0.z + a0.w*a0.w;
        ss += a1.x*a1.x + a1.y*a1.y + a1.z*a1.z + a1.w*a1.w;
        uint4 pk = { cvt_pk_bf16(a0.x, a0.y), cvt_pk_bf16(a0.z, a0.w),
                     cvt_pk_bf16(a1.x, a1.y), cvt_pk_bf16(a1.z, a1.w) };
        *(uint4*)(&As[0][arow * 32 + aslot * 8]) = pk;
    }
    __syncthreads();

    int buf = 0;
    for (int ks = 0; ks < NS; ks++) {
        const bool more = (ks + 1 < NS);
        float4 a0, a1;
        if (more) {
            stageB(buf ^ 1, ks + 1);
            a0 = *(const float4*)(xrow + (ks + 1) * 32);
            a1 = *(const float4*)(xrow + (ks + 1) * 32 + 4);
        }
        // compute on buf
        short8 af[4];
#pragma unroll
        for (int rf = 0; rf < 4; rf++) {
            const int row = 64 * wr + 16 * rf + l15;
            af[rf] = *(const short8*)(&As[buf][row * 32 + fslot * 8]);
        }
#pragma unroll
        for (int cf = 0; cf < 8; cf++) {
            const int brow = 128 * wc + 16 * cf + l15;
            const short8 bfv = *(const short8*)(&Bs[buf][brow * 32 + fslot * 8]);
#pragma unroll
            for (int rf = 0; rf < 4; rf++)
                acc[rf][cf] = __builtin_amdgcn_mfma_f32_16x16x32_bf16(af[rf], bfv, acc[rf][cf], 0, 0, 0);
        }
        if (more) {
            ss += a0.x*a0.x + a0.y*a0.y + a0.z*a0.z + a0.w*a0.w;
            ss += a1.x*a1.x + a1.y*a1.y + a1.z*a1.z + a1.w*a1.w;
            uint4 pk = { cvt_pk_bf16(a0.x, a0.y), cvt_pk_bf16(a0.z, a0.w),
                         cvt_pk_bf16(a1.x, a1.y), cvt_pk_bf16(a1.z, a1.w) };
            *(uint4*)(&As[buf ^ 1][arow * 32 + aslot * 8]) = pk;
        }
        __syncthreads();
        buf ^= 1;
    }

    // ||x_row||^2 finalize (reduce over the 4 threads sharing a row: lane bits 0,1)
    float* xn2 = (float*)(&As[1][0]);          // alias dead A buffer (512B)
    float sred = ss;
    sred += __shfl_xor(sred, 1);
    sred += __shfl_xor(sred, 2);
    if (aseg == 0) xn2[arow] = sred;
    __syncthreads();

    // epilogue: lane holds rows {64wr+16rf+4l4+r}, cols {128wc+16cf+l15}; cf<4 = w, cf+4 = beta
    float xr[4][4];
#pragma unroll
    for (int rf = 0; rf < 4; rf++)
#pragma unroll
        for (int r = 0; r < 4; r++)
            xr[rf][r] = xn2[64 * wr + 16 * rf + 4 * l4 + r];

    float hxa[4][4] = {{0}}, mua[4][4] = {{0}}, s2a[4][4] = {{0}};
#pragma unroll
    for (int q = 0; q < 4; q++) {
        const int k = 64 * wc + 16 * q + l15;
        const float wn2v = prms[k];
        const float g2v  = prms[KC + k];
        const float hv   = prms[2 * KC + k];
        const float alv  = prms[3 * KC + k];
        const float s2v  = prms[4 * KC + k];
#pragma unroll
        for (int rf = 0; rf < 4; rf++) {
            const f32x4 aw = acc[rf][q];
            const f32x4 ab = acc[rf][q + 4];
#pragma unroll
            for (int r = 0; r < 4; r++) {
                float d2 = xr[rf][r] - 2.f * aw[r] + wn2v;
                float a  = __expf(-g2v * d2);
                float ah = a * hv;
                hxa[rf][r] += ah;
                mua[rf][r] += (ab[r] + alv) * ah;
                s2a[rf][r] += s2v * ah * ah;
            }
        }
    }

    // reduce over the 16 lanes (same rows, different k), stash per-wc partials
    float (*part)[128][3] = (float (*)[128][3])(&As[0][0]);   // alias dead A buffer (6KB)
#pragma unroll
    for (int rf = 0; rf < 4; rf++) {
#pragma unroll
        for (int r = 0; r < 4; r++) {
            float h = hxa[rf][r], m = mua[rf][r], g = s2a[rf][r];
#pragma unroll
            for (int msk = 1; msk < 16; msk <<= 1) {
                h += __shfl_xor(h, msk);
                m += __shfl_xor(m, msk);
                g += __shfl_xor(g, msk);
            }
            if (l15 == 0) {
                const int row = 64 * wr + 16 * rf + 4 * l4 + r;
                part[wc][row][0] = h;
                part[wc][row][1] = m;
                part[wc][row][2] = g;
            }
        }
    }
    __syncthreads();
    if (tid < 128) {
        float h = part[0][tid][0] + part[1][tid][0] + part[2][tid][0] + part[3][tid][0];
        float m = part[0][tid][1] + part[1][tid][1] + part[2][tid][1] + part[3][tid][1];
        float g = part[0][tid][2] + part[1][tid][2] + part[2][tid][2] + part[3][tid][2];
        const int R = row0 + tid;
        out[(size_t)s * NT + R]       = m / h;         // mux_s
        out[(size_t)(4 + s) * NT + R] = g / (h * h);   // sig2x_s
        out[(size_t)(8 + s) * NT + R] = h;             // hx_s
    }
}

// ---------------- combine: rows 3 of each output ----------------
__global__ void combine_kernel(const float* __restrict__ d0, const float* __restrict__ d1,
                               const float* __restrict__ d2, float* out) {
    const int t = blockIdx.x * 256 + threadIdx.x;
    const float sd0 = 1.f / (1.f + __expf(-d0[0]));
    const float sd1 = 1.f / (1.f + __expf(-d1[0]));
    const float sd2 = 1.f / (1.f + __expf(-d2[0]));
    const float hx0 = out[(size_t)8 * NT + t];
    const float hx1 = out[(size_t)9 * NT + t];
    const float hx2 = out[(size_t)10 * NT + t];
    const float c0 = hx0 * sd0, c1 = hx1 * sd1, c2 = hx2 * sd2;
    const float den = c0 + c1 + c2;
    const float muc = out[(size_t)0 * NT + t] * c0 + out[(size_t)1 * NT + t] * c1 + out[(size_t)2 * NT + t] * c2;
    const float sgc = out[(size_t)4 * NT + t] * c0 * c0 + out[(size_t)5 * NT + t] * c1 * c1 + out[(size_t)6 * NT + t] * c2 * c2;
    out[(size_t)3 * NT + t]  = muc / den;
    out[(size_t)7 * NT + t]  = sgc / (den * den);
    out[(size_t)11 * NT + t] = den;
}

extern "C" void kernel_launch(void* const* d_in, const int* in_sizes, int n_in,
                              void* d_out, int out_size, void* d_ws, size_t ws_size,
                              hipStream_t stream) {
    // input order per source i: x=8i, alpha=8i+1, beta=8i+2, sig=8i+3, eta=8i+4, gam=8i+5, w=8i+6, disc=8i+7
    const float* x0 = (const float*)d_in[0];
    const float* x1 = (const float*)d_in[8];
    const float* x2 = (const float*)d_in[16];

    unsigned short* bc = (unsigned short*)d_ws;                 // 512*(512+256+128) ushorts = 917504 B
    float* prmAll = (float*)((char*)d_ws + 917504);             // 3*5*256 floats
    float* out = (float*)d_out;

    const int Ps[3] = {512, 256, 128};
    const size_t bcoff[3] = {0, 512 * 512, 512 * 512 + 512 * 256};
    for (int s = 0; s < 3; s++) {
        const float* alpha = (const float*)d_in[8 * s + 1];
        const float* beta  = (const float*)d_in[8 * s + 2];
        const float* sig   = (const float*)d_in[8 * s + 3];
        const float* eta   = (const float*)d_in[8 * s + 4];
        const float* gam   = (const float*)d_in[8 * s + 5];
        const float* w     = (const float*)d_in[8 * s + 6];
        prep_kernel<<<512, 128, 0, stream>>>(w, beta, alpha, sig, eta, gam,
                                             bc + bcoff[s], prmAll + s * 5 * KC, Ps[s]);
    }
    fused_kernel<<<1536, 512, 0, stream>>>(x0, x1, x2, bc, prmAll, out);
    combine_kernel<<<256, 256, 0, stream>>>((const float*)d_in[7], (const float*)d_in[15],
                                            (const float*)d_in[23], out);
}

// Round 3
// 155.889 us; speedup vs baseline: 1.1819x; 1.0147x over previous
//
#include <hip/hip_runtime.h>
#include <hip/hip_bf16.h>

typedef __attribute__((ext_vector_type(8))) short short8;
typedef __attribute__((ext_vector_type(4))) float f32x4;

#define NT 65536
#define KC 256

__device__ __forceinline__ unsigned short f2bf(float f) {
    union { float f; unsigned int u; } v; v.f = f;
    unsigned int u = v.u;
    unsigned int r = (u + 0x7fffu + ((u >> 16) & 1u)) >> 16;  // RNE
    return (unsigned short)r;
}

__device__ __forceinline__ unsigned int cvt_pk_bf16(float lo, float hi) {
    unsigned int r;
    asm("v_cvt_pk_bf16_f32 %0, %1, %2" : "=v"(r) : "v"(lo), "v"(hi));
    return r;
}

// ---------------- prep: build bf16 B panel (w/beta interleaved in 64-groups) + per-k params ----------------
__global__ void prep_kernel(const float* __restrict__ w, const float* __restrict__ beta,
                            const float* __restrict__ alpha, const float* __restrict__ sig,
                            const float* __restrict__ eta, const float* __restrict__ gam,
                            unsigned short* __restrict__ bc, float* __restrict__ prm, int P) {
    __shared__ float red[2];
    const int n = blockIdx.x;          // 0..511
    const int tid = threadIdx.x;       // 128 threads
    const int gidx = n >> 7;
    const int j = n & 127;
    const int k = 64 * gidx + (j & 63);
    const bool isw = (j < 64);
    const float* src = (isw ? w : beta) + (size_t)k * P;
    unsigned short* dst = bc + (size_t)n * P;
    float ss = 0.f;
    for (int c = tid; c < P; c += 128) {
        float f = src[c];
        dst[c] = f2bf(f);
        if (isw) ss += f * f;
    }
#pragma unroll
    for (int m = 1; m < 64; m <<= 1) ss += __shfl_xor(ss, m);
    if ((tid & 63) == 0) red[tid >> 6] = ss;
    __syncthreads();
    if (isw && tid == 0) prm[k] = red[0] + red[1];
    if (n == 0) {
        for (int kk = tid; kk < KC; kk += 128) {
            float g = gam[kk], e = eta[kk];
            prm[KC + kk]     = g * g;
            prm[2 * KC + kk] = e * e;
            prm[3 * KC + kk] = alpha[kk];
            prm[4 * KC + kk] = sig[kk] * sig[kk];
        }
    }
}

// ---------------- fused: GEMM (x@w^T, x@beta^T) + RBF epilogue, per source ----------------
// grid: 3072 blocks (bx%3 = source, bx/3 = 64-row block), 256 threads = 4 waves (one per SIMD).
// block tile: 64 rows x 512 cols; wave wc owns 64 x 128 (cols [128wc,128wc+128)).
// K streamed in 32-steps, A+B double-buffered LDS (72 KB) -> 2 blocks/CU co-resident:
// one block's MFMA phase hides the other's stage/vmcnt-drain latency.
// LDS rows 64B (32 ushorts); 16B slots XOR-swizzled: phys_slot = log_slot ^ ((row>>1)&3).
// B staged via global_load_lds (linear LDS dest) with pre-swizzled GLOBAL source.
__global__ __launch_bounds__(256, 2)
void fused_kernel(const float* __restrict__ x0, const float* __restrict__ x1, const float* __restrict__ x2,
                  const unsigned short* __restrict__ bcAll, const float* __restrict__ prmAll,
                  float* __restrict__ out) {
    __shared__ unsigned short As[2][64 * 32];
    __shared__ unsigned short Bs[2][512 * 32];

    const int bx = blockIdx.x;
    const int s  = bx % 3;
    const int mb = bx / 3;                 // 0..1023
    const int P  = (s == 0) ? 512 : ((s == 1) ? 256 : 128);
    const int NS = P >> 5;
    const float* x = (s == 0) ? x0 : ((s == 1) ? x1 : x2);
    const unsigned short* Bc = bcAll + ((s == 0) ? 0 : ((s == 1) ? (512 * 512) : (512 * 512 + 512 * 256)));
    const float* prms = prmAll + s * 5 * KC;
    const int row0 = mb * 64;

    const int tid  = threadIdx.x;          // 0..255
    const int lane = tid & 63;
    const int wc   = tid >> 6;             // wave id 0..3 = column quarter
    const int l15 = lane & 15;
    const int l4  = lane >> 4;             // 0..3
    const int fslot = l4 ^ ((l15 >> 1) & 3);   // swizzled slot for fragment reads

    f32x4 acc[4][8];
#pragma unroll
    for (int rf = 0; rf < 4; rf++)
#pragma unroll
        for (int cf = 0; cf < 8; cf++) acc[rf][cf] = (f32x4){0.f, 0.f, 0.f, 0.f};

    // A staging: thread -> (row = tid>>2 in 0..63, 8-float seg = tid&3), swizzled slot on write
    const int arow = tid >> 2;
    const int aseg = tid & 3;
    const int aslot = aseg ^ ((arow >> 1) & 3);
    const float* xrow = x + (size_t)(row0 + arow) * P + aseg * 8;
    float ss = 0.f;

    // B staging via global_load_lds: 8 insts/thread, physical u = i*256+tid, LDS byte = u*16 (linear).
    auto stageB = [&](int nb, int ks) {
#pragma unroll
        for (int i = 0; i < 8; i++) {
            const int u = i * 256 + tid;
            const int r = u >> 2;
            const int sl = (u & 3) ^ ((r >> 1) & 3);
            const unsigned short* src = Bc + (size_t)r * P + ks * 32 + sl * 8;
            unsigned short* dstbase = &Bs[nb][i * 2048 + wc * 512];   // ushort units
            __builtin_amdgcn_global_load_lds((const __attribute__((address_space(1))) void*)src,
                                             (__attribute__((address_space(3))) void*)dstbase, 16, 0, 0);
        }
    };

    // prologue: stage ks=0 into buf 0
    stageB(0, 0);
    {
        float4 a0 = *(const float4*)(xrow);
        float4 a1 = *(const float4*)(xrow + 4);
        ss += a0.x*a0.x + a0.y*a0.y + a0.z*a0.z + a0.w*a0.w;
        ss += a1.x*a1.x + a1.y*a1.y + a1.z*a1.z + a1.w*a1.w;
        uint4 pk = { cvt_pk_bf16(a0.x, a0.y), cvt_pk_bf16(a0.z, a0.w),
                     cvt_pk_bf16(a1.x, a1.y), cvt_pk_bf16(a1.z, a1.w) };
        *(uint4*)(&As[0][arow * 32 + aslot * 8]) = pk;
    }
    __syncthreads();

    int buf = 0;
    for (int ks = 0; ks < NS; ks++) {
        const bool more = (ks + 1 < NS);
        float4 a0, a1;
        if (more) {
            stageB(buf ^ 1, ks + 1);
            a0 = *(const float4*)(xrow + (ks + 1) * 32);
            a1 = *(const float4*)(xrow + (ks + 1) * 32 + 4);
        }
        // compute on buf
        short8 af[4];
#pragma unroll
        for (int rf = 0; rf < 4; rf++)
            af[rf] = *(const short8*)(&As[buf][(16 * rf + l15) * 32 + fslot * 8]);
#pragma unroll
        for (int cf = 0; cf < 8; cf++) {
            const int brow = 128 * wc + 16 * cf + l15;
            const short8 bfv = *(const short8*)(&Bs[buf][brow * 32 + fslot * 8]);
#pragma unroll
            for (int rf = 0; rf < 4; rf++)
                acc[rf][cf] = __builtin_amdgcn_mfma_f32_16x16x32_bf16(af[rf], bfv, acc[rf][cf], 0, 0, 0);
        }
        if (more) {
            ss += a0.x*a0.x + a0.y*a0.y + a0.z*a0.z + a0.w*a0.w;
            ss += a1.x*a1.x + a1.y*a1.y + a1.z*a1.z + a1.w*a1.w;
            uint4 pk = { cvt_pk_bf16(a0.x, a0.y), cvt_pk_bf16(a0.z, a0.w),
                         cvt_pk_bf16(a1.x, a1.y), cvt_pk_bf16(a1.z, a1.w) };
            *(uint4*)(&As[buf ^ 1][arow * 32 + aslot * 8]) = pk;
        }
        __syncthreads();
        buf ^= 1;
    }

    // ||x_row||^2 finalize (4 threads per row share partials)
    float* xn2 = (float*)(&As[1][0]);          // alias dead A buffer
    float sred = ss;
    sred += __shfl_xor(sred, 1);
    sred += __shfl_xor(sred, 2);
    if (aseg == 0) xn2[arow] = sred;
    __syncthreads();

    // epilogue: lane holds rows {16rf+4l4+r}, cols {128wc+16cf+l15}; cf<4 = w, cf+4 = beta
    float xr[4][4];
#pragma unroll
    for (int rf = 0; rf < 4; rf++)
#pragma unroll
        for (int r = 0; r < 4; r++)
            xr[rf][r] = xn2[16 * rf + 4 * l4 + r];

    float hxa[4][4] = {{0}}, mua[4][4] = {{0}}, s2a[4][4] = {{0}};
#pragma unroll
    for (int q = 0; q < 4; q++) {
        const int k = 64 * wc + 16 * q + l15;
        const float wn2v = prms[k];
        const float g2v  = prms[KC + k];
        const float hv   = prms[2 * KC + k];
        const float alv  = prms[3 * KC + k];
        const float s2v  = prms[4 * KC + k];
#pragma unroll
        for (int rf = 0; rf < 4; rf++) {
            const f32x4 aw = acc[rf][q];
            const f32x4 ab = acc[rf][q + 4];
#pragma unroll
            for (int r = 0; r < 4; r++) {
                float d2 = xr[rf][r] - 2.f * aw[r] + wn2v;
                float a  = __expf(-g2v * d2);
                float ah = a * hv;
                hxa[rf][r] += ah;
                mua[rf][r] += (ab[r] + alv) * ah;
                s2a[rf][r] += s2v * ah * ah;
            }
        }
    }

    // reduce over the 16 lanes (same rows, different k), stash per-wave partials
    float (*part)[64][3] = (float (*)[64][3])(&As[0][0]);   // alias dead A buffer (3 KB)
#pragma unroll
    for (int rf = 0; rf < 4; rf++) {
#pragma unroll
        for (int r = 0; r < 4; r++) {
            float h = hxa[rf][r], m = mua[rf][r], g = s2a[rf][r];
#pragma unroll
            for (int msk = 1; msk < 16; msk <<= 1) {
                h += __shfl_xor(h, msk);
                m += __shfl_xor(m, msk);
                g += __shfl_xor(g, msk);
            }
            if (l15 == 0) {
                const int row = 16 * rf + 4 * l4 + r;
                part[wc][row][0] = h;
                part[wc][row][1] = m;
                part[wc][row][2] = g;
            }
        }
    }
    __syncthreads();
    if (tid < 64) {
        float h = part[0][tid][0] + part[1][tid][0] + part[2][tid][0] + part[3][tid][0];
        float m = part[0][tid][1] + part[1][tid][1] + part[2][tid][1] + part[3][tid][1];
        float g = part[0][tid][2] + part[1][tid][2] + part[2][tid][2] + part[3][tid][2];
        const int R = row0 + tid;
        out[(size_t)s * NT + R]       = m / h;         // mux_s
        out[(size_t)(4 + s) * NT + R] = g / (h * h);   // sig2x_s
        out[(size_t)(8 + s) * NT + R] = h;             // hx_s
    }
}

// ---------------- combine: rows 3 of each output ----------------
__global__ void combine_kernel(const float* __restrict__ d0, const float* __restrict__ d1,
                               const float* __restrict__ d2, float* out) {
    const int t = blockIdx.x * 256 + threadIdx.x;
    const float sd0 = 1.f / (1.f + __expf(-d0[0]));
    const float sd1 = 1.f / (1.f + __expf(-d1[0]));
    const float sd2 = 1.f / (1.f + __expf(-d2[0]));
    const float hx0 = out[(size_t)8 * NT + t];
    const float hx1 = out[(size_t)9 * NT + t];
    const float hx2 = out[(size_t)10 * NT + t];
    const float c0 = hx0 * sd0, c1 = hx1 * sd1, c2 = hx2 * sd2;
    const float den = c0 + c1 + c2;
    const float muc = out[(size_t)0 * NT + t] * c0 + out[(size_t)1 * NT + t] * c1 + out[(size_t)2 * NT + t] * c2;
    const float sgc = out[(size_t)4 * NT + t] * c0 * c0 + out[(size_t)5 * NT + t] * c1 * c1 + out[(size_t)6 * NT + t] * c2 * c2;
    out[(size_t)3 * NT + t]  = muc / den;
    out[(size_t)7 * NT + t]  = sgc / (den * den);
    out[(size_t)11 * NT + t] = den;
}

extern "C" void kernel_launch(void* const* d_in, const int* in_sizes, int n_in,
                              void* d_out, int out_size, void* d_ws, size_t ws_size,
                              hipStream_t stream) {
    // input order per source i: x=8i, alpha=8i+1, beta=8i+2, sig=8i+3, eta=8i+4, gam=8i+5, w=8i+6, disc=8i+7
    const float* x0 = (const float*)d_in[0];
    const float* x1 = (const float*)d_in[8];
    const float* x2 = (const float*)d_in[16];

    unsigned short* bc = (unsigned short*)d_ws;                 // 512*(512+256+128) ushorts = 917504 B
    float* prmAll = (float*)((char*)d_ws + 917504);             // 3*5*256 floats
    float* out = (float*)d_out;

    const int Ps[3] = {512, 256, 128};
    const size_t bcoff[3] = {0, 512 * 512, 512 * 512 + 512 * 256};
    for (int s = 0; s < 3; s++) {
        const float* alpha = (const float*)d_in[8 * s + 1];
        const float* beta  = (const float*)d_in[8 * s + 2];
        const float* sig   = (const float*)d_in[8 * s + 3];
        const float* eta   = (const float*)d_in[8 * s + 4];
        const float* gam   = (const float*)d_in[8 * s + 5];
        const float* w     = (const float*)d_in[8 * s + 6];
        prep_kernel<<<512, 128, 0, stream>>>(w, beta, alpha, sig, eta, gam,
                                             bc + bcoff[s], prmAll + s * 5 * KC, Ps[s]);
    }
    fused_kernel<<<3072, 256, 0, stream>>>(x0, x1, x2, bc, prmAll, out);
    combine_kernel<<<256, 256, 0, stream>>>((const float*)d_in[7], (const float*)d_in[15],
                                            (const float*)d_in[23], out);
}

// Round 4
// 133.931 us; speedup vs baseline: 1.3757x; 1.1639x over previous
//
#include <hip/hip_runtime.h>
#include <hip/hip_bf16.h>

typedef __attribute__((ext_vector_type(8))) short short8;
typedef __attribute__((ext_vector_type(4))) float f32x4;

#define NT 65536

__device__ __forceinline__ unsigned short f2bf(float f) {
    union { float f; unsigned int u; } v; v.f = f;
    unsigned int u = v.u;
    unsigned int r = (u + 0x7fffu + ((u >> 16) & 1u)) >> 16;  // RNE
    return (unsigned short)r;
}

__device__ __forceinline__ unsigned int cvt_pk_bf16(float lo, float hi) {
    unsigned int r;
    asm("v_cvt_pk_bf16_f32 %0, %1, %2" : "=v"(r) : "v"(lo), "v"(hi));
    return r;
}

// ---------------- prep: bf16 B panel (wave-major layout) + per-k params ----------------
// Panel row n: wb = n>>5 (wave-block 0..15), j = n&31; j<16 -> w[wb*16 + j], else beta[wb*16 + j-16]
// prm per source (5*256 floats): [0:256)=||w_k||^2, [256)=gam^2, [512)=eta^2, [768)=alpha, [1024)=sig^2
__global__ void prep_kernel(const float* __restrict__ w, const float* __restrict__ beta,
                            const float* __restrict__ alpha, const float* __restrict__ sig,
                            const float* __restrict__ eta, const float* __restrict__ gam,
                            unsigned short* __restrict__ bc, float* __restrict__ prm, int P) {
    __shared__ float red[2];
    const int n = blockIdx.x;          // 0..511
    const int tid = threadIdx.x;       // 128 threads
    const int wb = n >> 5;
    const int j = n & 31;
    const bool isw = (j < 16);
    const int k = wb * 16 + (j & 15);
    const float* src = (isw ? w : beta) + (size_t)k * P;
    unsigned short* dst = bc + (size_t)n * P;
    float ss = 0.f;
    for (int c = tid; c < P; c += 128) {
        float f = src[c];
        dst[c] = f2bf(f);
        if (isw) ss += f * f;
    }
#pragma unroll
    for (int m = 1; m < 64; m <<= 1) ss += __shfl_xor(ss, m);
    if ((tid & 63) == 0) red[tid >> 6] = ss;
    __syncthreads();
    if (isw && tid == 0) prm[k] = red[0] + red[1];
    if (n == 0) {
        for (int kk = tid; kk < 256; kk += 128) {
            float g = gam[kk], e = eta[kk];
            prm[256 + kk]  = g * g;
            prm[512 + kk]  = e * e;
            prm[768 + kk]  = alpha[kk];
            prm[1024 + kk] = sig[kk] * sig[kk];
        }
    }
}

// ---------------- fused per-source: persistent-B-in-registers GEMM + RBF epilogue ----------------
// grid 256 blocks x 512 thr (8 waves). h = bx&1 (k-half), rg = bx>>1 (row-group).
// Wave wv owns 16 k's (wb = h*8+wv): B frags (w + beta strips, full K) resident in VGPRs.
// Block processes 8 row-tiles of 64 rows (tiles rg + 128*tt). A staged fp32->bf16 into
// double-buffered LDS; granule loads issued WIN k-steps ahead of cvt+ds_write (latency hiding).
// MFMA operands swapped: mfma(Bf, af) -> C row = k (register idx), col = x-row (lane&15):
// epilogue k-reduction = register adds + 2 shuffles. Partial (h,m,g) per k-half -> workspace.
// LDS 16B-slot swizzle: phys_slot = slot ^ (row&7) (write & read) -> 2-way max on frag reads.
template<int P>
__global__ __launch_bounds__(512, 2)
void fused_src(const float* __restrict__ x, const unsigned short* __restrict__ Bc,
               const float* __restrict__ prm, float* __restrict__ pws) {
    constexpr int KS  = P / 32;              // MFMA k-steps per tile
    constexpr int IST = P / 64;              // staging granules per thread per tile
    constexpr int WIN = (P == 256) ? 4 : 2;  // load->consume distance (reg window)
    __shared__ unsigned short As[2][64 * P];
    __shared__ float part[8][64][3];
    __shared__ float xn2s[2][64];

    const int bx = blockIdx.x;
    const int h  = bx & 1;
    const int rg = bx >> 1;                  // 0..127
    const int tid = threadIdx.x, lane = tid & 63, wv = tid >> 6;
    const int l15 = lane & 15, l4 = lane >> 4;
    const int wb = h * 8 + wv;

    // ---- persistent B fragments (A-operand layout: row = strip-row l15, k-off = 8*l4) ----
    short8 Bf[2][KS];
#pragma unroll
    for (int st = 0; st < 2; st++)
#pragma unroll
        for (int ks = 0; ks < KS; ks++)
            Bf[st][ks] = *(const short8*)(Bc + (size_t)(wb * 32 + st * 16 + l15) * P + ks * 32 + l4 * 8);

    // ---- per-lane params for k = wb*16 + 4*l4 + j ----
    const int kb = wb * 16 + 4 * l4;
    const f32x4 wn2 = *(const f32x4*)(prm + kb);
    const f32x4 g2  = *(const f32x4*)(prm + 256 + kb);
    const f32x4 hv  = *(const f32x4*)(prm + 512 + kb);
    const f32x4 alv = *(const f32x4*)(prm + 768 + kb);
    const f32x4 s2v = *(const f32x4*)(prm + 1024 + kb);

    float* pw = pws + (size_t)h * 3 * NT;

    // staging geometry: thread t -> row = t>>3 (0..63), slots (t&7) + 8*i, i < IST
    const int srow = tid >> 3;
    const int ssl0 = tid & 7;

    // ---- prologue: stage tile 0 into buf 0 ----
    {
        const int row0 = rg * 64;
        float4 pa[IST], pb[IST];
#pragma unroll
        for (int i = 0; i < IST; i++) {
            const float* gp = x + (size_t)(row0 + srow) * P + (ssl0 + 8 * i) * 8;
            pa[i] = *(const float4*)(gp);
            pb[i] = *(const float4*)(gp + 4);
        }
        float ssacc = 0.f;
#pragma unroll
        for (int i = 0; i < IST; i++) {
            float4 a0 = pa[i], a1 = pb[i];
            ssacc += a0.x*a0.x + a0.y*a0.y + a0.z*a0.z + a0.w*a0.w
                   + a1.x*a1.x + a1.y*a1.y + a1.z*a1.z + a1.w*a1.w;
            uint4 pk = { cvt_pk_bf16(a0.x, a0.y), cvt_pk_bf16(a0.z, a0.w),
                         cvt_pk_bf16(a1.x, a1.y), cvt_pk_bf16(a1.z, a1.w) };
            const int slot = ssl0 + 8 * i;
            *(uint4*)(&As[0][srow * P + ((slot ^ (srow & 7)) << 3)]) = pk;
        }
        ssacc += __shfl_xor(ssacc, 1);
        ssacc += __shfl_xor(ssacc, 2);
        ssacc += __shfl_xor(ssacc, 4);
        if (ssl0 == 0) xn2s[0][srow] = ssacc;
    }
    __syncthreads();

    int buf = 0;
    for (int tt = 0; tt < 8; tt++) {
        const int tile = rg + 128 * tt;
        const int row0 = tile * 64;
        const bool more = (tt < 7);
        const int nrow0 = (tile + 128) * 64;

        f32x4 acc[2][4];
#pragma unroll
        for (int st = 0; st < 2; st++)
#pragma unroll
            for (int rf = 0; rf < 4; rf++) acc[st][rf] = (f32x4){0.f, 0.f, 0.f, 0.f};

        float4 gfa[WIN], gfb[WIN];
        float ssacc = 0.f;

#pragma unroll
        for (int ks = 0; ks < KS; ks++) {
            // consume granule ks-WIN (cvt + swizzled ds_write into buf^1, ||x||^2 partial)
            if (more && ks >= WIN && (ks - WIN) < IST) {
                const int i = ks - WIN;
                float4 a0 = gfa[i % WIN], a1 = gfb[i % WIN];
                ssacc += a0.x*a0.x + a0.y*a0.y + a0.z*a0.z + a0.w*a0.w
                       + a1.x*a1.x + a1.y*a1.y + a1.z*a1.z + a1.w*a1.w;
                uint4 pk = { cvt_pk_bf16(a0.x, a0.y), cvt_pk_bf16(a0.z, a0.w),
                             cvt_pk_bf16(a1.x, a1.y), cvt_pk_bf16(a1.z, a1.w) };
                const int slot = ssl0 + 8 * i;
                *(uint4*)(&As[buf ^ 1][srow * P + ((slot ^ (srow & 7)) << 3)]) = pk;
            }
            // issue granule ks loads for next tile
            if (more && ks < IST) {
                const float* gp = x + (size_t)(nrow0 + srow) * P + (ssl0 + 8 * ks) * 8;
                gfa[ks % WIN] = *(const float4*)(gp);
                gfb[ks % WIN] = *(const float4*)(gp + 4);
            }
            // fragments + MFMA (A-operand = resident B, B-operand = x frag)
            short8 af[4];
#pragma unroll
            for (int rf = 0; rf < 4; rf++) {
                const int row = 16 * rf + l15;
                af[rf] = *(const short8*)(&As[buf][row * P + (((ks * 4 + l4) ^ (row & 7)) << 3)]);
            }
#pragma unroll
            for (int rf = 0; rf < 4; rf++) {
                acc[0][rf] = __builtin_amdgcn_mfma_f32_16x16x32_bf16(Bf[0][ks], af[rf], acc[0][rf], 0, 0, 0);
                acc[1][rf] = __builtin_amdgcn_mfma_f32_16x16x32_bf16(Bf[1][ks], af[rf], acc[1][rf], 0, 0, 0);
            }
        }

        // finalize next tile's ||x||^2 (8 threads share a row)
        if (more) {
            ssacc += __shfl_xor(ssacc, 1);
            ssacc += __shfl_xor(ssacc, 2);
            ssacc += __shfl_xor(ssacc, 4);
            if (ssl0 == 0) xn2s[buf ^ 1][srow] = ssacc;
        }

        // epilogue: lane holds x-row = 16rf + l15 (col), k = kb + j (row/register)
#pragma unroll
        for (int rf = 0; rf < 4; rf++) {
            const int row = 16 * rf + l15;
            const float xv = xn2s[buf][row];
            float hs = 0.f, ms = 0.f, gs = 0.f;
#pragma unroll
            for (int j = 0; j < 4; j++) {
                float d2 = xv - 2.f * acc[0][rf][j] + wn2[j];
                float a  = __expf(-g2[j] * d2);
                float ah = a * hv[j];
                hs += ah;
                ms += (acc[1][rf][j] + alv[j]) * ah;
                gs += s2v[j] * ah * ah;
            }
            hs += __shfl_xor(hs, 16); hs += __shfl_xor(hs, 32);
            ms += __shfl_xor(ms, 16); ms += __shfl_xor(ms, 32);
            gs += __shfl_xor(gs, 16); gs += __shfl_xor(gs, 32);
            if (l4 == 0) { part[wv][row][0] = hs; part[wv][row][1] = ms; part[wv][row][2] = gs; }
        }
        __syncthreads();
        if (tid < 192) {
            const int v = tid >> 6, r = tid & 63;
            float sum = 0.f;
#pragma unroll
            for (int w8 = 0; w8 < 8; w8++) sum += part[w8][r][v];
            pw[(size_t)v * NT + row0 + r] = sum;
        }
        __syncthreads();
        buf ^= 1;
    }
}

// ---------------- combine: all outputs from partials ----------------
__global__ void combine_kernel(const float* __restrict__ pws,
                               const float* __restrict__ d0, const float* __restrict__ d1,
                               const float* __restrict__ d2, float* __restrict__ out) {
    const int t = blockIdx.x * 256 + threadIdx.x;
    float mux[3], s2x[3], hx[3];
#pragma unroll
    for (int s = 0; s < 3; s++) {
        const float* b = pws + (size_t)s * 6 * NT;
        const float hh = b[t] + b[(size_t)3 * NT + t];
        const float mm = b[(size_t)1 * NT + t] + b[(size_t)4 * NT + t];
        const float gg = b[(size_t)2 * NT + t] + b[(size_t)5 * NT + t];
        mux[s] = mm / hh; s2x[s] = gg / (hh * hh); hx[s] = hh;
        out[(size_t)s * NT + t]       = mux[s];
        out[(size_t)(4 + s) * NT + t] = s2x[s];
        out[(size_t)(8 + s) * NT + t] = hh;
    }
    const float sd0 = 1.f / (1.f + __expf(-d0[0]));
    const float sd1 = 1.f / (1.f + __expf(-d1[0]));
    const float sd2 = 1.f / (1.f + __expf(-d2[0]));
    const float c0 = hx[0] * sd0, c1 = hx[1] * sd1, c2 = hx[2] * sd2;
    const float den = c0 + c1 + c2;
    const float muc = mux[0] * c0 + mux[1] * c1 + mux[2] * c2;
    const float sgc = s2x[0] * c0 * c0 + s2x[1] * c1 * c1 + s2x[2] * c2 * c2;
    out[(size_t)3 * NT + t]  = muc / den;
    out[(size_t)7 * NT + t]  = sgc / (den * den);
    out[(size_t)11 * NT + t] = den;
}

extern "C" void kernel_launch(void* const* d_in, const int* in_sizes, int n_in,
                              void* d_out, int out_size, void* d_ws, size_t ws_size,
                              hipStream_t stream) {
    // input order per source i: x=8i, alpha=8i+1, beta=8i+2, sig=8i+3, eta=8i+4, gam=8i+5, w=8i+6, disc=8i+7
    const float* x0 = (const float*)d_in[0];
    const float* x1 = (const float*)d_in[8];
    const float* x2 = (const float*)d_in[16];

    unsigned short* bc = (unsigned short*)d_ws;                  // 512*(512+256+128) ushorts = 917504 B
    float* prmAll = (float*)((char*)d_ws + 917504);              // 3*1280 floats = 15360 B
    float* pws    = (float*)((char*)d_ws + 917504 + 15360);      // 3*6*NT floats = 4.72 MB
    float* out = (float*)d_out;

    const int Ps[3] = {512, 256, 128};
    const size_t bcoff[3] = {0, 512 * 512, 512 * 512 + 512 * 256};
    for (int s = 0; s < 3; s++) {
        prep_kernel<<<512, 128, 0, stream>>>((const float*)d_in[8 * s + 6], (const float*)d_in[8 * s + 2],
                                             (const float*)d_in[8 * s + 1], (const float*)d_in[8 * s + 3],
                                             (const float*)d_in[8 * s + 4], (const float*)d_in[8 * s + 5],
                                             bc + bcoff[s], prmAll + s * 1280, Ps[s]);
    }
    fused_src<512><<<256, 512, 0, stream>>>(x0, bc + bcoff[0], prmAll,          pws);
    fused_src<256><<<256, 512, 0, stream>>>(x1, bc + bcoff[1], prmAll + 1280,   pws + (size_t)6 * NT);
    fused_src<128><<<256, 512, 0, stream>>>(x2, bc + bcoff[2], prmAll + 2560,   pws + (size_t)12 * NT);
    combine_kernel<<<256, 256, 0, stream>>>(pws, (const float*)d_in[7], (const float*)d_in[15],
                                            (const float*)d_in[23], out);
}